// Round 1
// baseline (3117.550 us; speedup 1.0000x reference)
//
#include <hip/hip_runtime.h>

#define N_EDGES_CONST 800000

// ---------------- degree ----------------
__global__ __launch_bounds__(256) void k_deg(const int* __restrict__ ei,
                                             float* __restrict__ deg, int nE) {
    int e = blockIdx.x * 256 + threadIdx.x;
    if (e < nE) atomicAdd(&deg[ei[nE + e]], 1.0f);
}

// ------------- scatter-add of 128-dim features: out[dst] += feat[src] -------------
__global__ __launch_bounds__(256) void k_scatter(const float* __restrict__ feat,
                                                 const int* __restrict__ ei,
                                                 float* __restrict__ out, int nE) {
    size_t idx = (size_t)blockIdx.x * 256 + threadIdx.x;
    if (idx >= (size_t)nE * 32) return;
    int e = (int)(idx >> 5);
    int p = (int)(idx & 31);
    int s = ei[e];
    int d = ei[nE + e];
    float4 v = *(const float4*)(feat + (size_t)s * 128 + p * 4);
    float* o = out + (size_t)d * 128 + p * 4;
    atomicAdd(o + 0, v.x);
    atomicAdd(o + 1, v.y);
    atomicAdd(o + 2, v.z);
    atomicAdd(o + 3, v.w);
}

// ------------- layer-1 fused dual GEMM: H = inv_deg*(Aagg@Wl^T) + Ax@Wr^T + b -------------
// K=128 fixed, M=256 (grid.y=4), tile 64 nodes x 64 feats, 256 threads, 4x4 microtile
__global__ __launch_bounds__(256) void k_gemm1(
    const float* __restrict__ Aagg, const float* __restrict__ Ax,
    const float* __restrict__ Wl,   const float* __restrict__ Wr,
    const float* __restrict__ bias, const float* __restrict__ deg,
    float* __restrict__ H, int n)
{
    __shared__ float sA1[64][33];
    __shared__ float sA2[64][33];
    __shared__ float sW1[64][33];
    __shared__ float sW2[64][33];
    const int bi = blockIdx.x * 64;
    const int bm = blockIdx.y * 64;
    const int tid = threadIdx.x;
    const int tx = tid & 15, ty = tid >> 4;
    float acc1[4][4] = {}, acc2[4][4] = {};
    const int r = tid >> 3;          // 0..31
    const int c = (tid & 7) << 2;    // 0,4,..,28

    for (int k0 = 0; k0 < 128; k0 += 32) {
        #pragma unroll
        for (int rr0 = 0; rr0 < 2; ++rr0) {
            const int rr = r + rr0 * 32;
            const int gi = bi + rr;
            float4 v1 = {0,0,0,0}, v2 = {0,0,0,0};
            if (gi < n) {
                v1 = *(const float4*)(Aagg + (size_t)gi * 128 + k0 + c);
                v2 = *(const float4*)(Ax   + (size_t)gi * 128 + k0 + c);
            }
            sA1[rr][c] = v1.x; sA1[rr][c+1] = v1.y; sA1[rr][c+2] = v1.z; sA1[rr][c+3] = v1.w;
            sA2[rr][c] = v2.x; sA2[rr][c+1] = v2.y; sA2[rr][c+2] = v2.z; sA2[rr][c+3] = v2.w;
            const int gm = bm + rr;  // < 256 always
            float4 w1 = *(const float4*)(Wl + (size_t)gm * 128 + k0 + c);
            float4 w2 = *(const float4*)(Wr + (size_t)gm * 128 + k0 + c);
            sW1[rr][c] = w1.x; sW1[rr][c+1] = w1.y; sW1[rr][c+2] = w1.z; sW1[rr][c+3] = w1.w;
            sW2[rr][c] = w2.x; sW2[rr][c+1] = w2.y; sW2[rr][c+2] = w2.z; sW2[rr][c+3] = w2.w;
        }
        __syncthreads();
        #pragma unroll 8
        for (int k = 0; k < 32; ++k) {
            float a1[4], a2[4], w1[4], w2[4];
            #pragma unroll
            for (int j = 0; j < 4; ++j) {
                a1[j] = sA1[ty*4+j][k];
                a2[j] = sA2[ty*4+j][k];
                w1[j] = sW1[tx*4+j][k];
                w2[j] = sW2[tx*4+j][k];
            }
            #pragma unroll
            for (int i2 = 0; i2 < 4; ++i2)
                #pragma unroll
                for (int j2 = 0; j2 < 4; ++j2) {
                    acc1[i2][j2] += a1[i2] * w1[j2];
                    acc2[i2][j2] += a2[i2] * w2[j2];
                }
        }
        __syncthreads();
    }
    #pragma unroll
    for (int i2 = 0; i2 < 4; ++i2) {
        const int gi = bi + ty*4 + i2;
        if (gi >= n) continue;
        const float invd = 1.0f / fmaxf(deg[gi], 1.0f);
        #pragma unroll
        for (int j2 = 0; j2 < 4; ++j2) {
            const int gm = bm + tx*4 + j2;
            H[(size_t)gi * 256 + gm] = acc1[i2][j2] * invd + acc2[i2][j2] + bias[gm];
        }
    }
}

// ------------- layer-2 dual GEMM (shared A): T2 = A@W1^T, R = A@W2^T -------------
// K=256 fixed, M=128 (grid.y=2)
__global__ __launch_bounds__(256) void k_gemm2(
    const float* __restrict__ A, const float* __restrict__ W1, const float* __restrict__ W2,
    float* __restrict__ T2, float* __restrict__ R, int n)
{
    __shared__ float sA[64][33];
    __shared__ float sW1[64][33];
    __shared__ float sW2[64][33];
    const int bi = blockIdx.x * 64;
    const int bm = blockIdx.y * 64;
    const int tid = threadIdx.x;
    const int tx = tid & 15, ty = tid >> 4;
    float acc1[4][4] = {}, acc2[4][4] = {};
    const int r = tid >> 3;
    const int c = (tid & 7) << 2;

    for (int k0 = 0; k0 < 256; k0 += 32) {
        #pragma unroll
        for (int rr0 = 0; rr0 < 2; ++rr0) {
            const int rr = r + rr0 * 32;
            const int gi = bi + rr;
            float4 v = {0,0,0,0};
            if (gi < n) v = *(const float4*)(A + (size_t)gi * 256 + k0 + c);
            sA[rr][c] = v.x; sA[rr][c+1] = v.y; sA[rr][c+2] = v.z; sA[rr][c+3] = v.w;
            const int gm = bm + rr;  // < 128 always
            float4 w1 = *(const float4*)(W1 + (size_t)gm * 256 + k0 + c);
            float4 w2 = *(const float4*)(W2 + (size_t)gm * 256 + k0 + c);
            sW1[rr][c] = w1.x; sW1[rr][c+1] = w1.y; sW1[rr][c+2] = w1.z; sW1[rr][c+3] = w1.w;
            sW2[rr][c] = w2.x; sW2[rr][c+1] = w2.y; sW2[rr][c+2] = w2.z; sW2[rr][c+3] = w2.w;
        }
        __syncthreads();
        #pragma unroll 8
        for (int k = 0; k < 32; ++k) {
            float a[4], w1[4], w2[4];
            #pragma unroll
            for (int j = 0; j < 4; ++j) {
                a[j]  = sA [ty*4+j][k];
                w1[j] = sW1[tx*4+j][k];
                w2[j] = sW2[tx*4+j][k];
            }
            #pragma unroll
            for (int i2 = 0; i2 < 4; ++i2)
                #pragma unroll
                for (int j2 = 0; j2 < 4; ++j2) {
                    acc1[i2][j2] += a[i2] * w1[j2];
                    acc2[i2][j2] += a[i2] * w2[j2];
                }
        }
        __syncthreads();
    }
    #pragma unroll
    for (int i2 = 0; i2 < 4; ++i2) {
        const int gi = bi + ty*4 + i2;
        if (gi >= n) continue;
        #pragma unroll
        for (int j2 = 0; j2 < 4; ++j2) {
            const int gm = bm + tx*4 + j2;
            T2[(size_t)gi * 128 + gm] = acc1[i2][j2];
            R [(size_t)gi * 128 + gm] = acc2[i2][j2];
        }
    }
}

// ------------- finalize: out = out*inv_deg + R + b2 -------------
__global__ __launch_bounds__(256) void k_finalize(float* __restrict__ out,
                                                  const float* __restrict__ R,
                                                  const float* __restrict__ b2,
                                                  const float* __restrict__ deg, int n) {
    size_t idx = (size_t)blockIdx.x * 256 + threadIdx.x;
    if (idx >= (size_t)n * 32) return;
    int i  = (int)(idx >> 5);
    int m4 = (int)(idx & 31);
    float invd = 1.0f / fmaxf(deg[i], 1.0f);
    float4 a  = *(const float4*)(out + idx * 4);
    float4 rr = *(const float4*)(R   + idx * 4);
    float4 b  = *(const float4*)(b2  + m4 * 4);
    float4 res;
    res.x = a.x * invd + rr.x + b.x;
    res.y = a.y * invd + rr.y + b.y;
    res.z = a.z * invd + rr.z + b.z;
    res.w = a.w * invd + rr.w + b.w;
    *(float4*)(out + idx * 4) = res;
}

extern "C" void kernel_launch(void* const* d_in, const int* in_sizes, int n_in,
                              void* d_out, int out_size, void* d_ws, size_t ws_size,
                              hipStream_t stream) {
    const float* x   = (const float*)d_in[0];
    const int*   ei  = (const int*)  d_in[1];
    const float* Wl1 = (const float*)d_in[2];
    const float* bl1 = (const float*)d_in[3];
    const float* Wr1 = (const float*)d_in[4];
    const float* Wl2 = (const float*)d_in[5];
    const float* bl2 = (const float*)d_in[6];
    const float* Wr2 = (const float*)d_in[7];
    float* out = (float*)d_out;

    const int nN = 50000;
    const int nE = in_sizes[1] / 2;   // 800000

    char* ws = (char*)d_ws;
    float* deg  = (float*)(ws);                               // 200 KB
    float* agg1 = (float*)(ws + (size_t)(1)  * (1 << 20));    // 25.6 MB (reused as t2)
    float* h    = (float*)(ws + (size_t)(27) * (1 << 20));    // 51.2 MB
    float* rbuf = (float*)(ws + (size_t)(79) * (1 << 20));    // 25.6 MB
    float* t2 = agg1;   // reuse: agg1 dead after k_gemm1

    // zero accumulators (ws/out are poisoned 0xAA before every call)
    hipMemsetAsync(deg,  0, (size_t)nN * 4, stream);
    hipMemsetAsync(agg1, 0, (size_t)nN * 128 * 4, stream);
    hipMemsetAsync(out,  0, (size_t)out_size * 4, stream);

    // degree
    k_deg<<<(nE + 255) / 256, 256, 0, stream>>>(ei, deg, nE);

    // layer-1 aggregation: agg1[dst] += x[src]
    {
        size_t total = (size_t)nE * 32;
        k_scatter<<<(int)((total + 255) / 256), 256, 0, stream>>>(x, ei, agg1, nE);
    }

    // h = inv*(agg1@Wl1^T) + x@Wr1^T + b1
    k_gemm1<<<dim3((nN + 63) / 64, 4), 256, 0, stream>>>(agg1, x, Wl1, Wr1, bl1, deg, h, nN);

    // t2 = h@Wl2^T ; rbuf = h@Wr2^T   (aggregate-after-transform: mean commutes with linear map)
    k_gemm2<<<dim3((nN + 63) / 64, 2), 256, 0, stream>>>(h, Wl2, Wr2, t2, rbuf, nN);

    // layer-2 aggregation directly into out: out[dst] += t2[src]
    {
        size_t total = (size_t)nE * 32;
        k_scatter<<<(int)((total + 255) / 256), 256, 0, stream>>>(t2, ei, out, nE);
    }

    // out = out*inv + rbuf + b2
    {
        size_t total = (size_t)nN * 32;
        k_finalize<<<(int)((total + 255) / 256), 256, 0, stream>>>(out, rbuf, bl2, deg, nN);
    }
}

// Round 2
// 559.862 us; speedup vs baseline: 5.5684x; 5.5684x over previous
//
#include <hip/hip_runtime.h>

// ---------------- histogram of dst ----------------
__global__ __launch_bounds__(256) void k_hist(const int* __restrict__ ei,
                                              int* __restrict__ cnt, int nE) {
    int e = blockIdx.x * 256 + threadIdx.x;
    if (e < nE) atomicAdd(&cnt[ei[nE + e]], 1);
}

// ---------------- hierarchical exclusive scan: rp = exscan(cnt) ----------------
__global__ __launch_bounds__(1024) void k_scan1(const int* __restrict__ cnt,
                                                int* __restrict__ rp,
                                                int* __restrict__ bsum, int n) {
    __shared__ int buf[1024];
    const int tid = threadIdx.x;
    const int i = blockIdx.x * 1024 + tid;
    int v = (i < n) ? cnt[i] : 0;
    buf[tid] = v;
    __syncthreads();
    #pragma unroll
    for (int off = 1; off < 1024; off <<= 1) {
        int t = 0;
        if (tid >= off) t = buf[tid - off];
        __syncthreads();
        if (tid >= off) buf[tid] += t;
        __syncthreads();
    }
    if (i < n) rp[i] = buf[tid] - v;   // exclusive within chunk
    if (tid == 1023) bsum[blockIdx.x] = buf[1023];
}

__global__ void k_scan2(const int* __restrict__ bsum, int* __restrict__ bofs,
                        int* __restrict__ rp, int nb, int n) {
    if (threadIdx.x == 0 && blockIdx.x == 0) {
        int run = 0;
        for (int b = 0; b < nb; ++b) { bofs[b] = run; run += bsum[b]; }
        rp[n] = run;
    }
}

__global__ __launch_bounds__(1024) void k_scan3(int* __restrict__ rp,
                                                const int* __restrict__ bofs, int n) {
    int i = blockIdx.x * 1024 + threadIdx.x;
    if (i < n) rp[i] += bofs[blockIdx.x];
}

// ---------------- counting-sort fill: srt[pos] = src, sorted by dst ----------------
__global__ __launch_bounds__(256) void k_fill(const int* __restrict__ ei,
                                              const int* __restrict__ rp,
                                              int* __restrict__ cur,
                                              int* __restrict__ srt, int nE) {
    int e = blockIdx.x * 256 + threadIdx.x;
    if (e >= nE) return;
    int d = ei[nE + e];
    int pos = rp[d] + atomicAdd(&cur[d], 1);
    srt[pos] = ei[e];
}

// ---------------- per-node wave gather (layer 1): out[i] = sum x[srt[e]] ----------------
__global__ __launch_bounds__(256) void k_gather1(const float* __restrict__ feat,
                                                 const int* __restrict__ srt,
                                                 const int* __restrict__ rp,
                                                 float* __restrict__ out, int n) {
    const int node = blockIdx.x * 4 + (threadIdx.x >> 6);
    if (node >= n) return;
    const int lane = threadIdx.x & 63;
    const int beg = rp[node], end = rp[node + 1];
    float2 acc = {0.f, 0.f};
    int e = beg;
    for (; e + 1 < end; e += 2) {
        int s0 = srt[e], s1 = srt[e + 1];
        float2 v0 = *(const float2*)(feat + (size_t)s0 * 128 + lane * 2);
        float2 v1 = *(const float2*)(feat + (size_t)s1 * 128 + lane * 2);
        acc.x += v0.x + v1.x;
        acc.y += v0.y + v1.y;
    }
    if (e < end) {
        int s0 = srt[e];
        float2 v0 = *(const float2*)(feat + (size_t)s0 * 128 + lane * 2);
        acc.x += v0.x;
        acc.y += v0.y;
    }
    *(float2*)(out + (size_t)node * 128 + lane * 2) = acc;
}

// ---------------- per-node wave gather (layer 2) + finalize ----------------
// out[i] = (sum t2[srt[e]]) * invd + rbuf[i] + b2
__global__ __launch_bounds__(256) void k_gather2(const float* __restrict__ t2,
                                                 const int* __restrict__ srt,
                                                 const int* __restrict__ rp,
                                                 const float* __restrict__ rbuf,
                                                 const float* __restrict__ b2,
                                                 float* __restrict__ out, int n) {
    const int node = blockIdx.x * 4 + (threadIdx.x >> 6);
    if (node >= n) return;
    const int lane = threadIdx.x & 63;
    const int beg = rp[node], end = rp[node + 1];
    float2 acc = {0.f, 0.f};
    int e = beg;
    for (; e + 1 < end; e += 2) {
        int s0 = srt[e], s1 = srt[e + 1];
        float2 v0 = *(const float2*)(t2 + (size_t)s0 * 128 + lane * 2);
        float2 v1 = *(const float2*)(t2 + (size_t)s1 * 128 + lane * 2);
        acc.x += v0.x + v1.x;
        acc.y += v0.y + v1.y;
    }
    if (e < end) {
        int s0 = srt[e];
        float2 v0 = *(const float2*)(t2 + (size_t)s0 * 128 + lane * 2);
        acc.x += v0.x;
        acc.y += v0.y;
    }
    const float invd = 1.0f / fmaxf((float)(end - beg), 1.0f);
    float2 rr = *(const float2*)(rbuf + (size_t)node * 128 + lane * 2);
    float2 bb = *(const float2*)(b2 + lane * 2);
    float2 res;
    res.x = acc.x * invd + rr.x + bb.x;
    res.y = acc.y * invd + rr.y + bb.y;
    *(float2*)(out + (size_t)node * 128 + lane * 2) = res;
}

// ------------- layer-1 fused dual GEMM: H = inv_deg*(Aagg@Wl^T) + Ax@Wr^T + b -------------
__global__ __launch_bounds__(256) void k_gemm1(
    const float* __restrict__ Aagg, const float* __restrict__ Ax,
    const float* __restrict__ Wl,   const float* __restrict__ Wr,
    const float* __restrict__ bias, const int* __restrict__ rp,
    float* __restrict__ H, int n)
{
    __shared__ float sA1[64][33];
    __shared__ float sA2[64][33];
    __shared__ float sW1[64][33];
    __shared__ float sW2[64][33];
    const int bi = blockIdx.x * 64;
    const int bm = blockIdx.y * 64;
    const int tid = threadIdx.x;
    const int tx = tid & 15, ty = tid >> 4;
    float acc1[4][4] = {}, acc2[4][4] = {};
    const int r = tid >> 3;
    const int c = (tid & 7) << 2;

    for (int k0 = 0; k0 < 128; k0 += 32) {
        #pragma unroll
        for (int rr0 = 0; rr0 < 2; ++rr0) {
            const int rr = r + rr0 * 32;
            const int gi = bi + rr;
            float4 v1 = {0,0,0,0}, v2 = {0,0,0,0};
            if (gi < n) {
                v1 = *(const float4*)(Aagg + (size_t)gi * 128 + k0 + c);
                v2 = *(const float4*)(Ax   + (size_t)gi * 128 + k0 + c);
            }
            sA1[rr][c] = v1.x; sA1[rr][c+1] = v1.y; sA1[rr][c+2] = v1.z; sA1[rr][c+3] = v1.w;
            sA2[rr][c] = v2.x; sA2[rr][c+1] = v2.y; sA2[rr][c+2] = v2.z; sA2[rr][c+3] = v2.w;
            const int gm = bm + rr;
            float4 w1 = *(const float4*)(Wl + (size_t)gm * 128 + k0 + c);
            float4 w2 = *(const float4*)(Wr + (size_t)gm * 128 + k0 + c);
            sW1[rr][c] = w1.x; sW1[rr][c+1] = w1.y; sW1[rr][c+2] = w1.z; sW1[rr][c+3] = w1.w;
            sW2[rr][c] = w2.x; sW2[rr][c+1] = w2.y; sW2[rr][c+2] = w2.z; sW2[rr][c+3] = w2.w;
        }
        __syncthreads();
        #pragma unroll 8
        for (int k = 0; k < 32; ++k) {
            float a1[4], a2[4], w1[4], w2[4];
            #pragma unroll
            for (int j = 0; j < 4; ++j) {
                a1[j] = sA1[ty*4+j][k];
                a2[j] = sA2[ty*4+j][k];
                w1[j] = sW1[tx*4+j][k];
                w2[j] = sW2[tx*4+j][k];
            }
            #pragma unroll
            for (int i2 = 0; i2 < 4; ++i2)
                #pragma unroll
                for (int j2 = 0; j2 < 4; ++j2) {
                    acc1[i2][j2] += a1[i2] * w1[j2];
                    acc2[i2][j2] += a2[i2] * w2[j2];
                }
        }
        __syncthreads();
    }
    #pragma unroll
    for (int i2 = 0; i2 < 4; ++i2) {
        const int gi = bi + ty*4 + i2;
        if (gi >= n) continue;
        const float invd = 1.0f / fmaxf((float)(rp[gi+1] - rp[gi]), 1.0f);
        #pragma unroll
        for (int j2 = 0; j2 < 4; ++j2) {
            const int gm = bm + tx*4 + j2;
            H[(size_t)gi * 256 + gm] = acc1[i2][j2] * invd + acc2[i2][j2] + bias[gm];
        }
    }
}

// ------------- layer-2 dual GEMM (shared A): T2 = A@W1^T, R = A@W2^T -------------
__global__ __launch_bounds__(256) void k_gemm2(
    const float* __restrict__ A, const float* __restrict__ W1, const float* __restrict__ W2,
    float* __restrict__ T2, float* __restrict__ R, int n)
{
    __shared__ float sA[64][33];
    __shared__ float sW1[64][33];
    __shared__ float sW2[64][33];
    const int bi = blockIdx.x * 64;
    const int bm = blockIdx.y * 64;
    const int tid = threadIdx.x;
    const int tx = tid & 15, ty = tid >> 4;
    float acc1[4][4] = {}, acc2[4][4] = {};
    const int r = tid >> 3;
    const int c = (tid & 7) << 2;

    for (int k0 = 0; k0 < 256; k0 += 32) {
        #pragma unroll
        for (int rr0 = 0; rr0 < 2; ++rr0) {
            const int rr = r + rr0 * 32;
            const int gi = bi + rr;
            float4 v = {0,0,0,0};
            if (gi < n) v = *(const float4*)(A + (size_t)gi * 256 + k0 + c);
            sA[rr][c] = v.x; sA[rr][c+1] = v.y; sA[rr][c+2] = v.z; sA[rr][c+3] = v.w;
            const int gm = bm + rr;
            float4 w1 = *(const float4*)(W1 + (size_t)gm * 256 + k0 + c);
            float4 w2 = *(const float4*)(W2 + (size_t)gm * 256 + k0 + c);
            sW1[rr][c] = w1.x; sW1[rr][c+1] = w1.y; sW1[rr][c+2] = w1.z; sW1[rr][c+3] = w1.w;
            sW2[rr][c] = w2.x; sW2[rr][c+1] = w2.y; sW2[rr][c+2] = w2.z; sW2[rr][c+3] = w2.w;
        }
        __syncthreads();
        #pragma unroll 8
        for (int k = 0; k < 32; ++k) {
            float a[4], w1[4], w2[4];
            #pragma unroll
            for (int j = 0; j < 4; ++j) {
                a[j]  = sA [ty*4+j][k];
                w1[j] = sW1[tx*4+j][k];
                w2[j] = sW2[tx*4+j][k];
            }
            #pragma unroll
            for (int i2 = 0; i2 < 4; ++i2)
                #pragma unroll
                for (int j2 = 0; j2 < 4; ++j2) {
                    acc1[i2][j2] += a[i2] * w1[j2];
                    acc2[i2][j2] += a[i2] * w2[j2];
                }
        }
        __syncthreads();
    }
    #pragma unroll
    for (int i2 = 0; i2 < 4; ++i2) {
        const int gi = bi + ty*4 + i2;
        if (gi >= n) continue;
        #pragma unroll
        for (int j2 = 0; j2 < 4; ++j2) {
            const int gm = bm + tx*4 + j2;
            T2[(size_t)gi * 128 + gm] = acc1[i2][j2];
            R [(size_t)gi * 128 + gm] = acc2[i2][j2];
        }
    }
}

extern "C" void kernel_launch(void* const* d_in, const int* in_sizes, int n_in,
                              void* d_out, int out_size, void* d_ws, size_t ws_size,
                              hipStream_t stream) {
    const float* x   = (const float*)d_in[0];
    const int*   ei  = (const int*)  d_in[1];
    const float* Wl1 = (const float*)d_in[2];
    const float* bl1 = (const float*)d_in[3];
    const float* Wr1 = (const float*)d_in[4];
    const float* Wl2 = (const float*)d_in[5];
    const float* bl2 = (const float*)d_in[6];
    const float* Wr2 = (const float*)d_in[7];
    float* out = (float*)d_out;

    const int nN = 50000;
    const int nE = in_sizes[1] / 2;   // 800000

    char* ws = (char*)d_ws;
    int*   rp   = (int*)  (ws);                                // (nN+1) ints
    int*   cnt  = (int*)  (ws + (size_t)256 * 1024);           // nN ints (hist, then cursor)
    int*   bsum = (int*)  (ws + (size_t)512 * 1024);           // 64 ints
    int*   bofs = (int*)  (ws + (size_t)512 * 1024 + 4096);    // 64 ints
    int*   srt  = (int*)  (ws + (size_t)1  * (1 << 20));       // nE ints, 3.2 MB
    float* agg1 = (float*)(ws + (size_t)5  * (1 << 20));       // 25.6 MB (reused as t2)
    float* h    = (float*)(ws + (size_t)31 * (1 << 20));       // 51.2 MB
    float* rbuf = (float*)(ws + (size_t)83 * (1 << 20));       // 25.6 MB
    float* t2 = agg1;

    const int nb = (nN + 1023) / 1024;   // 49

    // ---- build CSR (dst-sorted src list) ----
    hipMemsetAsync(cnt, 0, (size_t)nN * 4, stream);
    k_hist<<<(nE + 255) / 256, 256, 0, stream>>>(ei, cnt, nE);
    k_scan1<<<nb, 1024, 0, stream>>>(cnt, rp, bsum, nN);
    k_scan2<<<1, 64, 0, stream>>>(bsum, bofs, rp, nb, nN);
    k_scan3<<<nb, 1024, 0, stream>>>(rp, bofs, nN);
    hipMemsetAsync(cnt, 0, (size_t)nN * 4, stream);
    k_fill<<<(nE + 255) / 256, 256, 0, stream>>>(ei, rp, cnt, srt, nE);

    // ---- layer 1: gather-mean then dual GEMM ----
    k_gather1<<<(nN + 3) / 4, 256, 0, stream>>>(x, srt, rp, agg1, nN);
    k_gemm1<<<dim3((nN + 63) / 64, 4), 256, 0, stream>>>(agg1, x, Wl1, Wr1, bl1, rp, h, nN);

    // ---- layer 2: transform-then-aggregate (mean commutes with linear map) ----
    k_gemm2<<<dim3((nN + 63) / 64, 2), 256, 0, stream>>>(h, Wl2, Wr2, t2, rbuf, nN);
    k_gather2<<<(nN + 3) / 4, 256, 0, stream>>>(t2, srt, rp, rbuf, bl2, out, nN);
}

// Round 3
// 409.416 us; speedup vs baseline: 7.6146x; 1.3675x over previous
//
#include <hip/hip_runtime.h>

typedef __attribute__((ext_vector_type(4))) float f32x4;
typedef __attribute__((ext_vector_type(8))) short bf16x8;

__device__ inline ushort f2bf(float f) {
    uint u = __builtin_bit_cast(uint, f);
    u += 0x7fff + ((u >> 16) & 1);          // round-to-nearest-even
    return (ushort)(u >> 16);
}
__device__ inline float bf2f(ushort h) {
    uint u = ((uint)h) << 16;
    return __builtin_bit_cast(float, u);
}

// ---------------- histogram of dst ----------------
__global__ __launch_bounds__(256) void k_hist(const int* __restrict__ ei,
                                              int* __restrict__ cnt, int nE) {
    int e = blockIdx.x * 256 + threadIdx.x;
    if (e < nE) atomicAdd(&cnt[ei[nE + e]], 1);
}

// ---------------- hierarchical exclusive scan: rp = exscan(cnt) ----------------
__global__ __launch_bounds__(1024) void k_scan1(const int* __restrict__ cnt,
                                                int* __restrict__ rp,
                                                int* __restrict__ bsum, int n) {
    __shared__ int buf[1024];
    const int tid = threadIdx.x;
    const int i = blockIdx.x * 1024 + tid;
    int v = (i < n) ? cnt[i] : 0;
    buf[tid] = v;
    __syncthreads();
    #pragma unroll
    for (int off = 1; off < 1024; off <<= 1) {
        int t = 0;
        if (tid >= off) t = buf[tid - off];
        __syncthreads();
        if (tid >= off) buf[tid] += t;
        __syncthreads();
    }
    if (i < n) rp[i] = buf[tid] - v;
    if (tid == 1023) bsum[blockIdx.x] = buf[1023];
}

__global__ void k_scan2(const int* __restrict__ bsum, int* __restrict__ bofs,
                        int* __restrict__ rp, int nb, int n) {
    if (threadIdx.x == 0 && blockIdx.x == 0) {
        int run = 0;
        for (int b = 0; b < nb; ++b) { bofs[b] = run; run += bsum[b]; }
        rp[n] = run;
    }
}

__global__ __launch_bounds__(1024) void k_scan3(int* __restrict__ rp,
                                                const int* __restrict__ bofs, int n) {
    int i = blockIdx.x * 1024 + threadIdx.x;
    if (i < n) rp[i] += bofs[blockIdx.x];
}

// ---------------- counting-sort fill: srt[pos] = src, sorted by dst ----------------
__global__ __launch_bounds__(256) void k_fill(const int* __restrict__ ei,
                                              const int* __restrict__ rp,
                                              int* __restrict__ cur,
                                              int* __restrict__ srt, int nE) {
    int e = blockIdx.x * 256 + threadIdx.x;
    if (e >= nE) return;
    int d = ei[nE + e];
    int pos = rp[d] + atomicAdd(&cur[d], 1);
    srt[pos] = ei[e];
}

// ---------------- convert x -> bf16 into A1 columns [128:256) ----------------
__global__ __launch_bounds__(256) void k_cvt_x(const float* __restrict__ x,
                                               ushort* __restrict__ A1, int n) {
    int e4 = blockIdx.x * 256 + threadIdx.x;
    if (e4 >= n * 32) return;
    int i = e4 >> 5, c4 = e4 & 31;
    float4 v = *(const float4*)(x + (size_t)i * 128 + c4 * 4);
    ushort4 o;
    o.x = f2bf(v.x); o.y = f2bf(v.y); o.z = f2bf(v.z); o.w = f2bf(v.w);
    *(ushort4*)(A1 + (size_t)i * 256 + 128 + c4 * 4) = o;
}

// ---------------- convert+concat weights to bf16 ----------------
// W1cat[m][0:128]=Wl1[m], [128:256)=Wr1[m]   (m=0..255)
// W2cat[r][k]: r<128 -> Wl2[r][k]; r>=128 -> Wr2[r-128][k]   (k=0..255)
__global__ __launch_bounds__(256) void k_cvt_w(
    const float* __restrict__ Wl1, const float* __restrict__ Wr1,
    const float* __restrict__ Wl2, const float* __restrict__ Wr2,
    ushort* __restrict__ W1cat, ushort* __restrict__ W2cat) {
    int t = blockIdx.x * 256 + threadIdx.x;   // 0..32767
    int which = t >> 14;
    int r = (t >> 6) & 255;
    int kq = t & 63;
    const float* src;
    ushort* dst;
    if (which == 0) {
        src = (kq < 32) ? (Wl1 + (size_t)r * 128 + kq * 4)
                        : (Wr1 + (size_t)r * 128 + (kq - 32) * 4);
        dst = W1cat + (size_t)r * 256 + kq * 4;
    } else {
        src = (r < 128) ? (Wl2 + (size_t)r * 256 + kq * 4)
                        : (Wr2 + (size_t)(r - 128) * 256 + kq * 4);
        dst = W2cat + (size_t)r * 256 + kq * 4;
    }
    float4 v = *(const float4*)src;
    ushort4 o;
    o.x = f2bf(v.x); o.y = f2bf(v.y); o.z = f2bf(v.z); o.w = f2bf(v.w);
    *(ushort4*)dst = o;
}

// ---------------- gather1: A1[i][0:128) = mean_{src in N(i)} A1[src][128:256) ----------------
__global__ __launch_bounds__(256) void k_gather1(ushort* A1,
                                                 const int* __restrict__ srt,
                                                 const int* __restrict__ rp, int n) {
    const int node = blockIdx.x * 4 + (threadIdx.x >> 6);
    if (node >= n) return;
    const int lane = threadIdx.x & 63;
    const int beg = rp[node], end = rp[node + 1];
    float ax = 0.f, ay = 0.f;
    int e = beg;
    for (; e + 1 < end; e += 2) {
        int s0 = srt[e], s1 = srt[e + 1];
        uint v0 = *(const uint*)(A1 + (size_t)s0 * 256 + 128 + lane * 2);
        uint v1 = *(const uint*)(A1 + (size_t)s1 * 256 + 128 + lane * 2);
        ax += bf2f((ushort)v0) + bf2f((ushort)v1);
        ay += bf2f((ushort)(v0 >> 16)) + bf2f((ushort)(v1 >> 16));
    }
    if (e < end) {
        uint v0 = *(const uint*)(A1 + (size_t)srt[e] * 256 + 128 + lane * 2);
        ax += bf2f((ushort)v0);
        ay += bf2f((ushort)(v0 >> 16));
    }
    const float invd = 1.0f / fmaxf((float)(end - beg), 1.0f);
    uint o = ((uint)f2bf(ay * invd) << 16) | (uint)f2bf(ax * invd);
    *(uint*)(A1 + (size_t)node * 256 + lane * 2) = o;
}

// ---------------- gather2 + finalize: out[i] = mean(t2[nbrs]) + rbuf[i] + b2 ----------------
// H2 layout: [i][0:128)=t2 (bf16), [i][128:256)=rbuf (bf16)
__global__ __launch_bounds__(256) void k_gather2(const ushort* __restrict__ H2,
                                                 const int* __restrict__ srt,
                                                 const int* __restrict__ rp,
                                                 const float* __restrict__ b2,
                                                 float* __restrict__ out, int n) {
    const int node = blockIdx.x * 4 + (threadIdx.x >> 6);
    if (node >= n) return;
    const int lane = threadIdx.x & 63;
    const int beg = rp[node], end = rp[node + 1];
    float ax = 0.f, ay = 0.f;
    int e = beg;
    for (; e + 1 < end; e += 2) {
        int s0 = srt[e], s1 = srt[e + 1];
        uint v0 = *(const uint*)(H2 + (size_t)s0 * 256 + lane * 2);
        uint v1 = *(const uint*)(H2 + (size_t)s1 * 256 + lane * 2);
        ax += bf2f((ushort)v0) + bf2f((ushort)v1);
        ay += bf2f((ushort)(v0 >> 16)) + bf2f((ushort)(v1 >> 16));
    }
    if (e < end) {
        uint v0 = *(const uint*)(H2 + (size_t)srt[e] * 256 + lane * 2);
        ax += bf2f((ushort)v0);
        ay += bf2f((ushort)(v0 >> 16));
    }
    const float invd = 1.0f / fmaxf((float)(end - beg), 1.0f);
    uint rv = *(const uint*)(H2 + (size_t)node * 256 + 128 + lane * 2);
    float2 bb = *(const float2*)(b2 + lane * 2);
    float2 res;
    res.x = ax * invd + bf2f((ushort)rv) + bb.x;
    res.y = ay * invd + bf2f((ushort)(rv >> 16)) + bb.y;
    *(float2*)(out + (size_t)node * 128 + lane * 2) = res;
}

// ---------------- MFMA GEMM: O[n x 256] = A[n x 256] @ W[256 x 256]^T (+bias) ----------------
// BM=128, BN=128 (grid.y=2), 256 threads = 4 waves (2x2), wave tile 64x64, K=256 in LDS.
__global__ __launch_bounds__(256) void k_gemm_mfma(
    const ushort* __restrict__ A, const ushort* __restrict__ W,
    const float* __restrict__ bias, ushort* __restrict__ O, int n)
{
    __shared__ ushort sA[128][264];   // +8 bf16 pad: row stride 528B, 16B-aligned, conflict-free
    __shared__ ushort sW[128][264];
    const int bi = blockIdx.x * 128;
    const int bj = blockIdx.y * 128;
    const int tid = threadIdx.x;

    // stage A-tile and W-tile (global -> reg -> padded LDS)
    {
        const int r0 = tid >> 5;          // 0..7
        const int c  = (tid & 31) * 8;    // bf16 col, 16B chunks
        #pragma unroll
        for (int p = 0; p < 16; ++p) {
            const int row = p * 8 + r0;
            uint4 av = make_uint4(0, 0, 0, 0);
            if (bi + row < n) av = *(const uint4*)(A + (size_t)(bi + row) * 256 + c);
            *(uint4*)(&sA[row][c]) = av;
            uint4 wv = *(const uint4*)(W + (size_t)(bj + row) * 256 + c);
            *(uint4*)(&sW[row][c]) = wv;
        }
    }
    __syncthreads();

    const int wid = tid >> 6;
    const int lane = tid & 63;
    const int wm = (wid >> 1) * 64, wn = (wid & 1) * 64;
    const int lr = lane & 15;
    const int lk = (lane >> 4) * 8;

    f32x4 acc[4][4] = {};
    #pragma unroll
    for (int kk = 0; kk < 8; ++kk) {
        bf16x8 af[4], wf[4];
        #pragma unroll
        for (int mi = 0; mi < 4; ++mi)
            af[mi] = *(const bf16x8*)(&sA[wm + mi * 16 + lr][kk * 32 + lk]);
        #pragma unroll
        for (int ni = 0; ni < 4; ++ni)
            wf[ni] = *(const bf16x8*)(&sW[wn + ni * 16 + lr][kk * 32 + lk]);
        #pragma unroll
        for (int mi = 0; mi < 4; ++mi)
            #pragma unroll
            for (int ni = 0; ni < 4; ++ni)
                acc[mi][ni] = __builtin_amdgcn_mfma_f32_16x16x32_bf16(
                    af[mi], wf[ni], acc[mi][ni], 0, 0, 0);
    }

    // epilogue: C/D layout col=lane&15, row=(lane>>4)*4+j  [m89-verified]
    const int crow0 = (lane >> 4) * 4;
    const int ccol = lane & 15;
    #pragma unroll
    for (int mi = 0; mi < 4; ++mi) {
        #pragma unroll
        for (int ni = 0; ni < 4; ++ni) {
            const int ocol = bj + wn + ni * 16 + ccol;
            const float badd = bias ? bias[ocol] : 0.0f;
            #pragma unroll
            for (int j = 0; j < 4; ++j) {
                const int grow = bi + wm + mi * 16 + crow0 + j;
                if (grow < n)
                    O[(size_t)grow * 256 + ocol] = f2bf(acc[mi][ni][j] + badd);
            }
        }
    }
}

extern "C" void kernel_launch(void* const* d_in, const int* in_sizes, int n_in,
                              void* d_out, int out_size, void* d_ws, size_t ws_size,
                              hipStream_t stream) {
    const float* x   = (const float*)d_in[0];
    const int*   ei  = (const int*)  d_in[1];
    const float* Wl1 = (const float*)d_in[2];
    const float* bl1 = (const float*)d_in[3];
    const float* Wr1 = (const float*)d_in[4];
    const float* Wl2 = (const float*)d_in[5];
    const float* bl2 = (const float*)d_in[6];
    const float* Wr2 = (const float*)d_in[7];
    float* out = (float*)d_out;

    const int nN = 50000;
    const int nE = in_sizes[1] / 2;   // 800000

    char* ws = (char*)d_ws;
    int*    rp    = (int*)   (ws);                              // (nN+1) ints
    int*    cnt   = (int*)   (ws + (size_t)256 * 1024);
    int*    bsum  = (int*)   (ws + (size_t)512 * 1024);
    int*    bofs  = (int*)   (ws + (size_t)512 * 1024 + 4096);
    int*    srt   = (int*)   (ws + (size_t)1 * (1 << 20));      // 3.2 MB
    ushort* W1cat = (ushort*)(ws + (size_t)5 * (1 << 20));      // 128 KB
    ushort* W2cat = (ushort*)(ws + (size_t)5 * (1 << 20) + 256 * 1024);
    ushort* A1    = (ushort*)(ws + (size_t)6 * (1 << 20));      // 25.6 MB
    ushort* H     = (ushort*)(ws + (size_t)32 * (1 << 20));     // 25.6 MB
    ushort* H2    = (ushort*)(ws + (size_t)58 * (1 << 20));     // 25.6 MB

    const int nb = (nN + 1023) / 1024;   // 49

    // ---- build CSR (dst-sorted src list) ----
    hipMemsetAsync(cnt, 0, (size_t)nN * 4, stream);
    k_hist<<<(nE + 255) / 256, 256, 0, stream>>>(ei, cnt, nE);
    k_scan1<<<nb, 1024, 0, stream>>>(cnt, rp, bsum, nN);
    k_scan2<<<1, 64, 0, stream>>>(bsum, bofs, rp, nb, nN);
    k_scan3<<<nb, 1024, 0, stream>>>(rp, bofs, nN);
    hipMemsetAsync(cnt, 0, (size_t)nN * 4, stream);
    k_fill<<<(nE + 255) / 256, 256, 0, stream>>>(ei, rp, cnt, srt, nE);

    // ---- bf16 conversions ----
    k_cvt_x<<<(nN * 32 + 255) / 256, 256, 0, stream>>>(x, A1, nN);
    k_cvt_w<<<128, 256, 0, stream>>>(Wl1, Wr1, Wl2, Wr2, W1cat, W2cat);

    // ---- layer 1: gather-mean into A1[:,0:128), then single fused GEMM ----
    k_gather1<<<(nN + 3) / 4, 256, 0, stream>>>(A1, srt, rp, nN);
    k_gemm_mfma<<<dim3((nN + 127) / 128, 2), 256, 0, stream>>>(A1, W1cat, bl1, H, nN);

    // ---- layer 2: single stacked GEMM, then gather-mean + finalize ----
    k_gemm_mfma<<<dim3((nN + 127) / 128, 2), 256, 0, stream>>>(H, W2cat, nullptr, H2, nN);
    k_gather2<<<(nN + 3) / 4, 256, 0, stream>>>(H2, srt, rp, bl2, out, nN);
}

// Round 4
// 308.805 us; speedup vs baseline: 10.0955x; 1.3258x over previous
//
#include <hip/hip_runtime.h>

typedef __attribute__((ext_vector_type(4))) float f32x4;
typedef __attribute__((ext_vector_type(8))) short bf16x8;

__device__ inline ushort f2bf(float f) {
    uint u = __builtin_bit_cast(uint, f);
    u += 0x7fff + ((u >> 16) & 1);          // round-to-nearest-even
    return (ushort)(u >> 16);
}
__device__ inline float bf2f(ushort h) {
    uint u = ((uint)h) << 16;
    return __builtin_bit_cast(float, u);
}

// ---------------- histogram of dst ----------------
__global__ __launch_bounds__(256) void k_hist(const int* __restrict__ ei,
                                              int* __restrict__ cnt, int nE) {
    int e = blockIdx.x * 256 + threadIdx.x;
    if (e < nE) atomicAdd(&cnt[ei[nE + e]], 1);
}

// ---------------- hierarchical exclusive scan: rp = exscan(cnt) ----------------
__global__ __launch_bounds__(1024) void k_scan1(const int* __restrict__ cnt,
                                                int* __restrict__ rp,
                                                int* __restrict__ bsum, int n) {
    __shared__ int buf[1024];
    const int tid = threadIdx.x;
    const int i = blockIdx.x * 1024 + tid;
    int v = (i < n) ? cnt[i] : 0;
    buf[tid] = v;
    __syncthreads();
    #pragma unroll
    for (int off = 1; off < 1024; off <<= 1) {
        int t = 0;
        if (tid >= off) t = buf[tid - off];
        __syncthreads();
        if (tid >= off) buf[tid] += t;
        __syncthreads();
    }
    if (i < n) rp[i] = buf[tid] - v;
    if (tid == 1023) bsum[blockIdx.x] = buf[1023];
}

__global__ void k_scan2(const int* __restrict__ bsum, int* __restrict__ bofs,
                        int* __restrict__ rp, int nb, int n) {
    if (threadIdx.x == 0 && blockIdx.x == 0) {
        int run = 0;
        for (int b = 0; b < nb; ++b) { bofs[b] = run; run += bsum[b]; }
        rp[n] = run;
    }
}

__global__ __launch_bounds__(1024) void k_scan3(int* __restrict__ rp,
                                                const int* __restrict__ bofs, int n) {
    int i = blockIdx.x * 1024 + threadIdx.x;
    if (i < n) rp[i] += bofs[blockIdx.x];
}

// ---------------- counting-sort fill: srt[pos] = src, sorted by dst ----------------
__global__ __launch_bounds__(256) void k_fill(const int* __restrict__ ei,
                                              const int* __restrict__ rp,
                                              int* __restrict__ cur,
                                              int* __restrict__ srt, int nE) {
    int e = blockIdx.x * 256 + threadIdx.x;
    if (e >= nE) return;
    int d = ei[nE + e];
    int pos = rp[d] + atomicAdd(&cur[d], 1);
    srt[pos] = ei[e];
}

// ---------------- convert x -> bf16 into A1 columns [128:256) ----------------
__global__ __launch_bounds__(256) void k_cvt_x(const float* __restrict__ x,
                                               ushort* __restrict__ A1, int n) {
    int e4 = blockIdx.x * 256 + threadIdx.x;
    if (e4 >= n * 32) return;
    int i = e4 >> 5, c4 = e4 & 31;
    float4 v = *(const float4*)(x + (size_t)i * 128 + c4 * 4);
    ushort4 o;
    o.x = f2bf(v.x); o.y = f2bf(v.y); o.z = f2bf(v.z); o.w = f2bf(v.w);
    *(ushort4*)(A1 + (size_t)i * 256 + 128 + c4 * 4) = o;
}

// ---------------- convert+concat weights to bf16 ----------------
__global__ __launch_bounds__(256) void k_cvt_w(
    const float* __restrict__ Wl1, const float* __restrict__ Wr1,
    const float* __restrict__ Wl2, const float* __restrict__ Wr2,
    ushort* __restrict__ W1cat, ushort* __restrict__ W2cat) {
    int t = blockIdx.x * 256 + threadIdx.x;   // 0..32767
    int which = t >> 14;
    int r = (t >> 6) & 255;
    int kq = t & 63;
    const float* src;
    ushort* dst;
    if (which == 0) {
        src = (kq < 32) ? (Wl1 + (size_t)r * 128 + kq * 4)
                        : (Wr1 + (size_t)r * 128 + (kq - 32) * 4);
        dst = W1cat + (size_t)r * 256 + kq * 4;
    } else {
        src = (r < 128) ? (Wl2 + (size_t)r * 256 + kq * 4)
                        : (Wr2 + (size_t)(r - 128) * 256 + kq * 4);
        dst = W2cat + (size_t)r * 256 + kq * 4;
    }
    float4 v = *(const float4*)src;
    ushort4 o;
    o.x = f2bf(v.x); o.y = f2bf(v.y); o.z = f2bf(v.z); o.w = f2bf(v.w);
    *(ushort4*)dst = o;
}

// ---------------- gather1: A1[i][0:128) = mean_{src in N(i)} A1[src][128:256) ----------------
__global__ __launch_bounds__(256) void k_gather1(ushort* A1,
                                                 const int* __restrict__ srt,
                                                 const int* __restrict__ rp, int n) {
    const int node = blockIdx.x * 4 + (threadIdx.x >> 6);
    if (node >= n) return;
    const int lane = threadIdx.x & 63;
    const int beg = rp[node], end = rp[node + 1];
    float ax = 0.f, ay = 0.f;
    int e = beg;
    for (; e + 3 < end; e += 4) {
        int s0 = srt[e], s1 = srt[e + 1], s2 = srt[e + 2], s3 = srt[e + 3];
        uint v0 = *(const uint*)(A1 + (size_t)s0 * 256 + 128 + lane * 2);
        uint v1 = *(const uint*)(A1 + (size_t)s1 * 256 + 128 + lane * 2);
        uint v2 = *(const uint*)(A1 + (size_t)s2 * 256 + 128 + lane * 2);
        uint v3 = *(const uint*)(A1 + (size_t)s3 * 256 + 128 + lane * 2);
        ax += (bf2f((ushort)v0) + bf2f((ushort)v1)) + (bf2f((ushort)v2) + bf2f((ushort)v3));
        ay += (bf2f((ushort)(v0 >> 16)) + bf2f((ushort)(v1 >> 16)))
            + (bf2f((ushort)(v2 >> 16)) + bf2f((ushort)(v3 >> 16)));
    }
    for (; e < end; ++e) {
        uint v0 = *(const uint*)(A1 + (size_t)srt[e] * 256 + 128 + lane * 2);
        ax += bf2f((ushort)v0);
        ay += bf2f((ushort)(v0 >> 16));
    }
    const float invd = 1.0f / fmaxf((float)(end - beg), 1.0f);
    uint o = ((uint)f2bf(ay * invd) << 16) | (uint)f2bf(ax * invd);
    *(uint*)(A1 + (size_t)node * 256 + lane * 2) = o;
}

// ---------------- gather2 + finalize: out[i] = mean(t2[nbrs]) + rbuf[i] + b2 ----------------
__global__ __launch_bounds__(256) void k_gather2(const ushort* __restrict__ H2,
                                                 const int* __restrict__ srt,
                                                 const int* __restrict__ rp,
                                                 const float* __restrict__ b2,
                                                 float* __restrict__ out, int n) {
    const int node = blockIdx.x * 4 + (threadIdx.x >> 6);
    if (node >= n) return;
    const int lane = threadIdx.x & 63;
    const int beg = rp[node], end = rp[node + 1];
    float ax = 0.f, ay = 0.f;
    int e = beg;
    for (; e + 3 < end; e += 4) {
        int s0 = srt[e], s1 = srt[e + 1], s2 = srt[e + 2], s3 = srt[e + 3];
        uint v0 = *(const uint*)(H2 + (size_t)s0 * 256 + lane * 2);
        uint v1 = *(const uint*)(H2 + (size_t)s1 * 256 + lane * 2);
        uint v2 = *(const uint*)(H2 + (size_t)s2 * 256 + lane * 2);
        uint v3 = *(const uint*)(H2 + (size_t)s3 * 256 + lane * 2);
        ax += (bf2f((ushort)v0) + bf2f((ushort)v1)) + (bf2f((ushort)v2) + bf2f((ushort)v3));
        ay += (bf2f((ushort)(v0 >> 16)) + bf2f((ushort)(v1 >> 16)))
            + (bf2f((ushort)(v2 >> 16)) + bf2f((ushort)(v3 >> 16)));
    }
    for (; e < end; ++e) {
        uint v0 = *(const uint*)(H2 + (size_t)srt[e] * 256 + lane * 2);
        ax += bf2f((ushort)v0);
        ay += bf2f((ushort)(v0 >> 16));
    }
    const float invd = 1.0f / fmaxf((float)(end - beg), 1.0f);
    uint rv = *(const uint*)(H2 + (size_t)node * 256 + 128 + lane * 2);
    float2 bb = *(const float2*)(b2 + lane * 2);
    float2 res;
    res.x = ax * invd + bf2f((ushort)rv) + bb.x;
    res.y = ay * invd + bf2f((ushort)(rv >> 16)) + bb.y;
    *(float2*)(out + (size_t)node * 128 + lane * 2) = res;
}

// ---------------- MFMA GEMM: O[n x 256] = A[n x 256] @ W[256 x 256]^T (+bias) ----------------
// BM=64, N=256 full, 512 threads = 8 waves, wave tile 64x32.
// Only A staged in LDS (32 KB, XOR-swizzled byte^=(row&7)<<4); W read per-kk from L2
// (128 KB total, shared by all 782 blocks).
__global__ __launch_bounds__(512) void k_gemm_mfma(
    const ushort* __restrict__ A, const ushort* __restrict__ W,
    const float* __restrict__ bias, ushort* __restrict__ O, int n)
{
    __shared__ __align__(16) char sA[32768];   // 64 rows x 512 B, swizzled
    const int bi = blockIdx.x * 64;
    const int tid = threadIdx.x;

    // stage A-tile: linear coalesced global read, swizzled LDS write (rule #21: both-sides)
    #pragma unroll
    for (int p = 0; p < 4; ++p) {
        const int o = p * 8192 + tid * 16;     // linear byte offset in tile
        const int row = o >> 9;                // /512B
        const int cb = o & 511;
        // rows beyond n read padded workspace garbage; outputs for those rows are masked
        uint4 v = *(const uint4*)((const char*)A + (size_t)(bi + row) * 512 + cb);
        *(uint4*)(sA + row * 512 + (cb ^ ((row & 7) << 4))) = v;
    }
    __syncthreads();

    const int wid = tid >> 6;      // 0..7
    const int lane = tid & 63;
    const int wn = wid * 32;       // output-col base for this wave
    const int lr = lane & 15;
    const int lkb = (lane >> 4) * 16;   // byte offset of this lane's k-chunk (8 bf16 = 16 B)

    f32x4 acc[4][2] = {};
    #pragma unroll
    for (int kk = 0; kk < 8; ++kk) {
        bf16x8 wf[2], af[4];
        #pragma unroll
        for (int ni = 0; ni < 2; ++ni)
            wf[ni] = *(const bf16x8*)((const char*)W + (size_t)(wn + ni * 16 + lr) * 512 + kk * 64 + lkb);
        #pragma unroll
        for (int mi = 0; mi < 4; ++mi) {
            const int row = mi * 16 + lr;
            const int cb = (kk * 64 + lkb) ^ ((row & 7) << 4);
            af[mi] = *(const bf16x8*)(sA + row * 512 + cb);
        }
        #pragma unroll
        for (int mi = 0; mi < 4; ++mi)
            #pragma unroll
            for (int ni = 0; ni < 2; ++ni)
                acc[mi][ni] = __builtin_amdgcn_mfma_f32_16x16x32_bf16(
                    af[mi], wf[ni], acc[mi][ni], 0, 0, 0);
    }

    // epilogue: C/D layout col=lane&15, row=(lane>>4)*4+j  [m89-verified]
    const int crow0 = (lane >> 4) * 4;
    const int ccol = lane & 15;
    #pragma unroll
    for (int mi = 0; mi < 4; ++mi) {
        #pragma unroll
        for (int ni = 0; ni < 2; ++ni) {
            const int ocol = wn + ni * 16 + ccol;
            const float badd = bias ? bias[ocol] : 0.0f;
            #pragma unroll
            for (int j = 0; j < 4; ++j) {
                const int grow = bi + mi * 16 + crow0 + j;
                if (grow < n)
                    O[(size_t)grow * 256 + ocol] = f2bf(acc[mi][ni][j] + badd);
            }
        }
    }
}

extern "C" void kernel_launch(void* const* d_in, const int* in_sizes, int n_in,
                              void* d_out, int out_size, void* d_ws, size_t ws_size,
                              hipStream_t stream) {
    const float* x   = (const float*)d_in[0];
    const int*   ei  = (const int*)  d_in[1];
    const float* Wl1 = (const float*)d_in[2];
    const float* bl1 = (const float*)d_in[3];
    const float* Wr1 = (const float*)d_in[4];
    const float* Wl2 = (const float*)d_in[5];
    const float* bl2 = (const float*)d_in[6];
    const float* Wr2 = (const float*)d_in[7];
    float* out = (float*)d_out;

    const int nN = 50000;
    const int nE = in_sizes[1] / 2;   // 800000

    char* ws = (char*)d_ws;
    int*    rp    = (int*)   (ws);                              // (nN+1) ints
    int*    cnt   = (int*)   (ws + (size_t)256 * 1024);         // nN ints
    int*    cur   = (int*)   (ws + (size_t)456 * 1024);         // nN ints (contiguous w/ cnt)
    int*    bsum  = (int*)   (ws + (size_t)700 * 1024);
    int*    bofs  = (int*)   (ws + (size_t)700 * 1024 + 4096);
    int*    srt   = (int*)   (ws + (size_t)1 * (1 << 20));      // 3.2 MB
    ushort* W1cat = (ushort*)(ws + (size_t)5 * (1 << 20));      // 128 KB
    ushort* W2cat = (ushort*)(ws + (size_t)5 * (1 << 20) + 256 * 1024);
    ushort* A1    = (ushort*)(ws + (size_t)6 * (1 << 20));      // 25.6 MB (+pad rows to 50048)
    ushort* H     = (ushort*)(ws + (size_t)32 * (1 << 20));     // 25.6 MB (+pad)
    ushort* H2    = (ushort*)(ws + (size_t)58 * (1 << 20));     // 25.6 MB

    const int nb = (nN + 1023) / 1024;   // 49

    // ---- build CSR (dst-sorted src list) ----
    hipMemsetAsync(cnt, 0, (size_t)(456 - 256 + 200) * 1024 - (456 - 256) * 1024 + (size_t)nN * 4, stream); // cnt
    hipMemsetAsync(cur, 0, (size_t)nN * 4, stream);
    k_hist<<<(nE + 255) / 256, 256, 0, stream>>>(ei, cnt, nE);
    k_scan1<<<nb, 1024, 0, stream>>>(cnt, rp, bsum, nN);
    k_scan2<<<1, 64, 0, stream>>>(bsum, bofs, rp, nb, nN);
    k_scan3<<<nb, 1024, 0, stream>>>(rp, bofs, nN);
    k_fill<<<(nE + 255) / 256, 256, 0, stream>>>(ei, rp, cur, srt, nE);

    // ---- bf16 conversions ----
    k_cvt_x<<<(nN * 32 + 255) / 256, 256, 0, stream>>>(x, A1, nN);
    k_cvt_w<<<128, 256, 0, stream>>>(Wl1, Wr1, Wl2, Wr2, W1cat, W2cat);

    // ---- layer 1: gather-mean into A1[:,0:128), then single fused GEMM ----
    k_gather1<<<(nN + 3) / 4, 256, 0, stream>>>(A1, srt, rp, nN);
    k_gemm_mfma<<<(nN + 63) / 64, 512, 0, stream>>>(A1, W1cat, bl1, H, nN);

    // ---- layer 2: single stacked GEMM, then gather-mean + finalize ----
    k_gemm_mfma<<<(nN + 63) / 64, 512, 0, stream>>>(H, W2cat, nullptr, H2, nN);
    k_gather2<<<(nN + 3) / 4, 256, 0, stream>>>(H2, srt, rp, bl2, out, nN);
}

// Round 5
// 294.481 us; speedup vs baseline: 10.5866x; 1.0486x over previous
//
#include <hip/hip_runtime.h>

typedef __attribute__((ext_vector_type(4))) float f32x4;
typedef __attribute__((ext_vector_type(8))) short bf16x8;

__device__ inline ushort f2bf(float f) {
    uint u = __builtin_bit_cast(uint, f);
    u += 0x7fff + ((u >> 16) & 1);          // round-to-nearest-even
    return (ushort)(u >> 16);
}
__device__ inline float bf2f(ushort h) {
    uint u = ((uint)h) << 16;
    return __builtin_bit_cast(float, u);
}

#define GRP 8          // XCD count; blockIdx.x & 7 ~ XCD id under round-robin dispatch
#define NSLICE 6250    // 50000 / 8
#define CHUNK 2048     // edges per block-chunk

// ---------------- XCD-partitioned histogram of dst ----------------
__global__ __launch_bounds__(256) void k_hist_p(const int* __restrict__ ei,
                                                int* __restrict__ cnt, int nE) {
    const int g = blockIdx.x & 7;
    const int c = blockIdx.x >> 3;
    const int lo = g * NSLICE, hi = lo + NSLICE;
    #pragma unroll
    for (int p = 0; p < CHUNK / 256; ++p) {
        int e = c * CHUNK + p * 256 + threadIdx.x;
        if (e < nE) {
            int d = ei[nE + e];
            if (d >= lo && d < hi) atomicAdd(&cnt[d], 1);
        }
    }
}

// ---------------- hierarchical exclusive scan: rp = exscan(cnt) ----------------
__global__ __launch_bounds__(1024) void k_scan1(const int* __restrict__ cnt,
                                                int* __restrict__ rp,
                                                int* __restrict__ bsum, int n) {
    __shared__ int buf[1024];
    const int tid = threadIdx.x;
    const int i = blockIdx.x * 1024 + tid;
    int v = (i < n) ? cnt[i] : 0;
    buf[tid] = v;
    __syncthreads();
    #pragma unroll
    for (int off = 1; off < 1024; off <<= 1) {
        int t = 0;
        if (tid >= off) t = buf[tid - off];
        __syncthreads();
        if (tid >= off) buf[tid] += t;
        __syncthreads();
    }
    if (i < n) rp[i] = buf[tid] - v;
    if (tid == 1023) bsum[blockIdx.x] = buf[1023];
}

__global__ void k_scan2(const int* __restrict__ bsum, int* __restrict__ bofs,
                        int* __restrict__ rp, int nb, int n) {
    if (threadIdx.x == 0 && blockIdx.x == 0) {
        int run = 0;
        for (int b = 0; b < nb; ++b) { bofs[b] = run; run += bsum[b]; }
        rp[n] = run;
    }
}

__global__ __launch_bounds__(1024) void k_scan3(int* __restrict__ rp,
                                                const int* __restrict__ bofs, int n) {
    int i = blockIdx.x * 1024 + threadIdx.x;
    if (i < n) rp[i] += bofs[blockIdx.x];
}

// ---------------- XCD-partitioned counting-sort fill ----------------
__global__ __launch_bounds__(256) void k_fill_p(const int* __restrict__ ei,
                                                const int* __restrict__ rp,
                                                int* __restrict__ cur,
                                                int* __restrict__ srt, int nE) {
    const int g = blockIdx.x & 7;
    const int c = blockIdx.x >> 3;
    const int lo = g * NSLICE, hi = lo + NSLICE;
    #pragma unroll
    for (int p = 0; p < CHUNK / 256; ++p) {
        int e = c * CHUNK + p * 256 + threadIdx.x;
        if (e < nE) {
            int d = ei[nE + e];
            int s = ei[e];              // coalesced unconditional load
            if (d >= lo && d < hi) {
                int pos = rp[d] + atomicAdd(&cur[d], 1);
                srt[pos] = s;
            }
        }
    }
}

// ---------------- convert x -> bf16 into A1 columns [128:256) ----------------
__global__ __launch_bounds__(256) void k_cvt_x(const float* __restrict__ x,
                                               ushort* __restrict__ A1, int n) {
    int e4 = blockIdx.x * 256 + threadIdx.x;
    if (e4 >= n * 32) return;
    int i = e4 >> 5, c4 = e4 & 31;
    float4 v = *(const float4*)(x + (size_t)i * 128 + c4 * 4);
    ushort4 o;
    o.x = f2bf(v.x); o.y = f2bf(v.y); o.z = f2bf(v.z); o.w = f2bf(v.w);
    *(ushort4*)(A1 + (size_t)i * 256 + 128 + c4 * 4) = o;
}

// ---------------- convert+concat weights to bf16 ----------------
__global__ __launch_bounds__(256) void k_cvt_w(
    const float* __restrict__ Wl1, const float* __restrict__ Wr1,
    const float* __restrict__ Wl2, const float* __restrict__ Wr2,
    ushort* __restrict__ W1cat, ushort* __restrict__ W2cat) {
    int t = blockIdx.x * 256 + threadIdx.x;   // 0..32767
    int which = t >> 14;
    int r = (t >> 6) & 255;
    int kq = t & 63;
    const float* src;
    ushort* dst;
    if (which == 0) {
        src = (kq < 32) ? (Wl1 + (size_t)r * 128 + kq * 4)
                        : (Wr1 + (size_t)r * 128 + (kq - 32) * 4);
        dst = W1cat + (size_t)r * 256 + kq * 4;
    } else {
        src = (r < 128) ? (Wl2 + (size_t)r * 256 + kq * 4)
                        : (Wr2 + (size_t)(r - 128) * 256 + kq * 4);
        dst = W2cat + (size_t)r * 256 + kq * 4;
    }
    float4 v = *(const float4*)src;
    ushort4 o;
    o.x = f2bf(v.x); o.y = f2bf(v.y); o.z = f2bf(v.z); o.w = f2bf(v.w);
    *(ushort4*)dst = o;
}

// ---------------- gather1: A1[i][0:128) = mean_{src in N(i)} A1[src][128:256) ----------------
__global__ __launch_bounds__(256) void k_gather1(ushort* A1,
                                                 const int* __restrict__ srt,
                                                 const int* __restrict__ rp, int n) {
    const int node = blockIdx.x * 4 + (threadIdx.x >> 6);
    if (node >= n) return;
    const int lane = threadIdx.x & 63;
    const int beg = rp[node], end = rp[node + 1];
    float ax = 0.f, ay = 0.f;
    int e = beg;
    for (; e + 7 < end; e += 8) {
        uint v[8];
        #pragma unroll
        for (int q = 0; q < 8; ++q)
            v[q] = *(const uint*)(A1 + (size_t)srt[e + q] * 256 + 128 + lane * 2);
        #pragma unroll
        for (int q = 0; q < 8; ++q) {
            ax += bf2f((ushort)v[q]);
            ay += bf2f((ushort)(v[q] >> 16));
        }
    }
    for (; e < end; ++e) {
        uint v0 = *(const uint*)(A1 + (size_t)srt[e] * 256 + 128 + lane * 2);
        ax += bf2f((ushort)v0);
        ay += bf2f((ushort)(v0 >> 16));
    }
    const float invd = 1.0f / fmaxf((float)(end - beg), 1.0f);
    uint o = ((uint)f2bf(ay * invd) << 16) | (uint)f2bf(ax * invd);
    *(uint*)(A1 + (size_t)node * 256 + lane * 2) = o;
}

// ---------------- gather2 + finalize: out[i] = mean(t2[nbrs]) + rbuf[i] + b2 ----------------
__global__ __launch_bounds__(256) void k_gather2(const ushort* __restrict__ H2,
                                                 const int* __restrict__ srt,
                                                 const int* __restrict__ rp,
                                                 const float* __restrict__ b2,
                                                 float* __restrict__ out, int n) {
    const int node = blockIdx.x * 4 + (threadIdx.x >> 6);
    if (node >= n) return;
    const int lane = threadIdx.x & 63;
    const int beg = rp[node], end = rp[node + 1];
    float ax = 0.f, ay = 0.f;
    int e = beg;
    for (; e + 7 < end; e += 8) {
        uint v[8];
        #pragma unroll
        for (int q = 0; q < 8; ++q)
            v[q] = *(const uint*)(H2 + (size_t)srt[e + q] * 256 + lane * 2);
        #pragma unroll
        for (int q = 0; q < 8; ++q) {
            ax += bf2f((ushort)v[q]);
            ay += bf2f((ushort)(v[q] >> 16));
        }
    }
    for (; e < end; ++e) {
        uint v0 = *(const uint*)(H2 + (size_t)srt[e] * 256 + lane * 2);
        ax += bf2f((ushort)v0);
        ay += bf2f((ushort)(v0 >> 16));
    }
    const float invd = 1.0f / fmaxf((float)(end - beg), 1.0f);
    uint rv = *(const uint*)(H2 + (size_t)node * 256 + 128 + lane * 2);
    float2 bb = *(const float2*)(b2 + lane * 2);
    float2 res;
    res.x = ax * invd + bf2f((ushort)rv) + bb.x;
    res.y = ay * invd + bf2f((ushort)(rv >> 16)) + bb.y;
    *(float2*)(out + (size_t)node * 128 + lane * 2) = res;
}

// ---------------- fused 2-layer MFMA GEMM ----------------
// Per 64-row block:  Htile = A1tile @ W1^T + b1  (into LDS, bf16, swizzled)
//                    O     = Htile  @ W2^T       (to global)
// 512 threads = 8 waves, wave owns 64x32 output cols [wid*32, wid*32+32).
// A staged in LDS (32 KB, byte^=(row&7)<<4); W1/W2 read from L2 (128 KB each, shared).
__global__ __launch_bounds__(512, 4) void k_gemm_fused(
    const ushort* __restrict__ A, const ushort* __restrict__ W1,
    const ushort* __restrict__ W2, const float* __restrict__ b1,
    ushort* __restrict__ O, int n)
{
    __shared__ __align__(16) char sA[32768];   // 64 rows x 512 B, swizzled
    __shared__ __align__(16) char sH[32768];
    const int bi = blockIdx.x * 64;
    const int tid = threadIdx.x;

    // stage A-tile: linear coalesced global read, swizzled LDS write (rule #21)
    #pragma unroll
    for (int p = 0; p < 4; ++p) {
        const int o = p * 8192 + tid * 16;
        const int row = o >> 9;
        const int cb = o & 511;
        uint4 v = *(const uint4*)((const char*)A + (size_t)(bi + row) * 512 + cb);
        *(uint4*)(sA + row * 512 + (cb ^ ((row & 7) << 4))) = v;
    }
    __syncthreads();

    const int wid = tid >> 6;
    const int lane = tid & 63;
    const int wn = wid * 32;
    const int lr = lane & 15;
    const int lkb = (lane >> 4) * 16;
    const int crow0 = (lane >> 4) * 4;
    const int ccol = lane & 15;

    // ---- GEMM 1: H = A @ W1^T + b1 ----
    {
        f32x4 acc[4][2] = {};
        #pragma unroll
        for (int kk = 0; kk < 8; ++kk) {
            bf16x8 wf[2], af[4];
            #pragma unroll
            for (int ni = 0; ni < 2; ++ni)
                wf[ni] = *(const bf16x8*)((const char*)W1 + (size_t)(wn + ni * 16 + lr) * 512 + kk * 64 + lkb);
            #pragma unroll
            for (int mi = 0; mi < 4; ++mi) {
                const int row = mi * 16 + lr;
                af[mi] = *(const bf16x8*)(sA + row * 512 + ((kk * 64 + lkb) ^ ((row & 7) << 4)));
            }
            #pragma unroll
            for (int mi = 0; mi < 4; ++mi)
                #pragma unroll
                for (int ni = 0; ni < 2; ++ni)
                    acc[mi][ni] = __builtin_amdgcn_mfma_f32_16x16x32_bf16(
                        af[mi], wf[ni], acc[mi][ni], 0, 0, 0);
        }
        const float badd0 = b1[wn + ccol];
        const float badd1 = b1[wn + 16 + ccol];
        #pragma unroll
        for (int mi = 0; mi < 4; ++mi)
            #pragma unroll
            for (int ni = 0; ni < 2; ++ni) {
                const int col = wn + ni * 16 + ccol;
                const float badd = ni ? badd1 : badd0;
                #pragma unroll
                for (int j = 0; j < 4; ++j) {
                    const int row = mi * 16 + crow0 + j;
                    *(ushort*)(sH + row * 512 + ((col * 2) ^ ((row & 7) << 4))) =
                        f2bf(acc[mi][ni][j] + badd);
                }
            }
    }
    __syncthreads();

    // ---- GEMM 2: O = H @ W2^T ----
    {
        f32x4 acc[4][2] = {};
        #pragma unroll
        for (int kk = 0; kk < 8; ++kk) {
            bf16x8 wf[2], af[4];
            #pragma unroll
            for (int ni = 0; ni < 2; ++ni)
                wf[ni] = *(const bf16x8*)((const char*)W2 + (size_t)(wn + ni * 16 + lr) * 512 + kk * 64 + lkb);
            #pragma unroll
            for (int mi = 0; mi < 4; ++mi) {
                const int row = mi * 16 + lr;
                af[mi] = *(const bf16x8*)(sH + row * 512 + ((kk * 64 + lkb) ^ ((row & 7) << 4)));
            }
            #pragma unroll
            for (int mi = 0; mi < 4; ++mi)
                #pragma unroll
                for (int ni = 0; ni < 2; ++ni)
                    acc[mi][ni] = __builtin_amdgcn_mfma_f32_16x16x32_bf16(
                        af[mi], wf[ni], acc[mi][ni], 0, 0, 0);
        }
        #pragma unroll
        for (int mi = 0; mi < 4; ++mi)
            #pragma unroll
            for (int ni = 0; ni < 2; ++ni) {
                const int ocol = wn + ni * 16 + ccol;
                #pragma unroll
                for (int j = 0; j < 4; ++j) {
                    const int grow = bi + mi * 16 + crow0 + j;
                    if (grow < n)
                        O[(size_t)grow * 256 + ocol] = f2bf(acc[mi][ni][j]);
                }
            }
    }
}

extern "C" void kernel_launch(void* const* d_in, const int* in_sizes, int n_in,
                              void* d_out, int out_size, void* d_ws, size_t ws_size,
                              hipStream_t stream) {
    const float* x   = (const float*)d_in[0];
    const int*   ei  = (const int*)  d_in[1];
    const float* Wl1 = (const float*)d_in[2];
    const float* bl1 = (const float*)d_in[3];
    const float* Wr1 = (const float*)d_in[4];
    const float* Wl2 = (const float*)d_in[5];
    const float* bl2 = (const float*)d_in[6];
    const float* Wr2 = (const float*)d_in[7];
    float* out = (float*)d_out;

    const int nN = 50000;
    const int nE = in_sizes[1] / 2;   // 800000

    char* ws = (char*)d_ws;
    int*    rp    = (int*)   (ws);                              // (nN+1) ints
    int*    cnt   = (int*)   (ws + 262144);                     // nN ints
    int*    cur   = (int*)   (ws + 524288);                     // nN ints
    int*    bsum  = (int*)   (ws + 786432);
    int*    bofs  = (int*)   (ws + 790528);
    int*    srt   = (int*)   (ws + (size_t)1 * (1 << 20));      // 3.2 MB
    ushort* W1cat = (ushort*)(ws + (size_t)5 * (1 << 20));      // 128 KB
    ushort* W2cat = (ushort*)(ws + (size_t)5 * (1 << 20) + 256 * 1024);
    ushort* A1    = (ushort*)(ws + (size_t)6 * (1 << 20));      // 25.6 MB (+pad rows)
    ushort* H2    = (ushort*)(ws + (size_t)32 * (1 << 20));     // 25.6 MB (+pad rows)

    const int nb = (nN + 1023) / 1024;             // 49
    const int nChunks = (nE + CHUNK - 1) / CHUNK;  // 391

    // ---- build CSR (dst-sorted src list), XCD-partitioned ----
    hipMemsetAsync(ws + 262144, 0, 462144, stream);   // cnt + cur
    k_hist_p<<<nChunks * GRP, 256, 0, stream>>>(ei, cnt, nE);
    k_scan1<<<nb, 1024, 0, stream>>>(cnt, rp, bsum, nN);
    k_scan2<<<1, 64, 0, stream>>>(bsum, bofs, rp, nb, nN);
    k_scan3<<<nb, 1024, 0, stream>>>(rp, bofs, nN);
    k_fill_p<<<nChunks * GRP, 256, 0, stream>>>(ei, rp, cur, srt, nE);

    // ---- bf16 conversions ----
    k_cvt_x<<<(nN * 32 + 255) / 256, 256, 0, stream>>>(x, A1, nN);
    k_cvt_w<<<128, 256, 0, stream>>>(Wl1, Wr1, Wl2, Wr2, W1cat, W2cat);

    // ---- layer 1 aggregation, then fused dual-layer GEMM ----
    k_gather1<<<(nN + 3) / 4, 256, 0, stream>>>(A1, srt, rp, nN);
    k_gemm_fused<<<(nN + 63) / 64, 512, 0, stream>>>(A1, W1cat, W2cat, bl1, H2, nN);

    // ---- layer 2 aggregation + finalize ----
    k_gather2<<<(nN + 3) / 4, 256, 0, stream>>>(H2, srt, rp, bl2, out, nN);
}